// Round 1
// 404.696 us; speedup vs baseline: 1.1458x; 1.1458x over previous
//
#include <hip/hip_runtime.h>
#include <hip/hip_bf16.h>

typedef short short8 __attribute__((ext_vector_type(8)));
typedef short short4v __attribute__((ext_vector_type(4)));
typedef float floatx4 __attribute__((ext_vector_type(4)));

#define BB 256
#define OO 1024
#define HH 2048
#define SS 12
#define LSTRIDE 72   // 64 + 8 pad elems; 144 B rows, 16B-aligned

__device__ __forceinline__ __hip_bfloat16 f2b(float x) { return __float2bfloat16(x); }
__device__ __forceinline__ float sigf(float x) { return 1.0f / (1.0f + expf(-x)); }

__device__ __forceinline__ short8 cvt8v(float4 lo, float4 hi) {
    union { short8 s; __hip_bfloat16 h[8]; } u;
    u.h[0] = f2b(lo.x); u.h[1] = f2b(lo.y); u.h[2] = f2b(lo.z); u.h[3] = f2b(lo.w);
    u.h[4] = f2b(hi.x); u.h[5] = f2b(hi.y); u.h[6] = f2b(hi.z); u.h[7] = f2b(hi.w);
    return u.s;
}
__device__ __forceinline__ short4v cvt4v(float4 v) {
    union { short4v s; __hip_bfloat16 h[4]; } u;
    u.h[0] = f2b(v.x); u.h[1] = f2b(v.y); u.h[2] = f2b(v.z); u.h[3] = f2b(v.w);
    return u.s;
}

// ---------------------------------------------------------------------------
// Attention phase 1: logits + softmax -> wts[256][12]
// ---------------------------------------------------------------------------
__global__ __launch_bounds__(256)
void attn_logits(const float* __restrict__ x0,
                 const float* __restrict__ h00,
                 const float* __restrict__ attn_W,
                 const float* __restrict__ attn_b,
                 float* __restrict__ wts)
{
    const int b = blockIdx.x;
    const int tid = threadIdx.x;
    const int lane = tid & 63;
    const int wave = tid >> 6;

    float part[SS];
#pragma unroll
    for (int s = 0; s < SS; s++) part[s] = 0.f;

#pragma unroll
    for (int k = 0; k < 3; k++) {
        const int c = tid + (k << 8);
        float4 v = (k == 0) ? *(const float4*)(x0 + (size_t)b * OO + (c << 2))
                            : *(const float4*)(h00 + (size_t)b * HH + ((c - 256) << 2));
#pragma unroll
        for (int s = 0; s < SS; s++) {
            float4 w4 = *(const float4*)(attn_W + (size_t)s * (OO + HH) + (c << 2));
            part[s] += v.x * w4.x + v.y * w4.y + v.z * w4.z + v.w * w4.w;
        }
    }
#pragma unroll
    for (int s = 0; s < SS; s++) {
#pragma unroll
        for (int off = 32; off > 0; off >>= 1)
            part[s] += __shfl_down(part[s], off);
    }
    __shared__ float red[4][SS];
    if (lane == 0) {
#pragma unroll
        for (int s = 0; s < SS; s++) red[wave][s] = part[s];
    }
    __syncthreads();
    if (tid == 0) {
        float logits[SS];
        float mx = -1e30f;
        for (int s = 0; s < SS; s++) {
            logits[s] = red[0][s] + red[1][s] + red[2][s] + red[3][s] + attn_b[s];
            mx = fmaxf(mx, logits[s]);
        }
        float sum = 0.f;
        for (int s = 0; s < SS; s++) { logits[s] = expf(logits[s] - mx); sum += logits[s]; }
        float inv = 1.0f / sum;
        for (int s = 0; s < SS; s++) wts[b * SS + s] = logits[s] * inv;
    }
}

// ---------------------------------------------------------------------------
// Attention phase 2: attn_out[b,h] = sum_s wts[b,s]*enc[s,b,h]
// grid = 512: block = (b, h-half of 1024); 256 thr x float4.
// ---------------------------------------------------------------------------
__global__ __launch_bounds__(256)
void attn_apply(const float* __restrict__ enc,
                const float* __restrict__ wts,
                float* __restrict__ attn_out)
{
    const int b = blockIdx.x >> 1;
    const int half = blockIdx.x & 1;
    const int tid = threadIdx.x;
    __shared__ float w[SS];
    if (tid < SS) w[tid] = wts[b * SS + tid];
    __syncthreads();
    const int h = (half << 10) + (tid << 2);
    float4 a = {0.f, 0.f, 0.f, 0.f};
#pragma unroll
    for (int s = 0; s < SS; s++) {
        float4 e = *(const float4*)(enc + ((size_t)(s * BB + b) * HH) + h);
        float ws = w[s];
        a.x += ws * e.x; a.y += ws * e.y; a.z += ws * e.z; a.w += ws * e.w;
    }
    *(float4*)(attn_out + (size_t)b * HH + h) = a;
}

// ---------------------------------------------------------------------------
// Dual-segment GEMM: C[256,N] = act(A1@W1^T + A2@W2^T + b1 + b2)
// fp32 I/O, bf16 MFMA. BM=16, BN=32, BK=64. 256 thr = 4 waves:
// wave = (colfrag cf = w&1, k-half kh = w>>1); k-split reduced via LDS.
// grid (N/32, 16) -> 512 blocks = 2 decoupled blocks/CU.
// ---------------------------------------------------------------------------
template<int K1, int K2, bool RELU>
__global__ __launch_bounds__(256)
void gemm_dual(const float* __restrict__ A1,
               const float* __restrict__ W1, int ldw1, int ofs1,
               const float* __restrict__ A2,
               const float* __restrict__ W2, int ldw2, int ofs2,
               const float* __restrict__ bias1,
               const float* __restrict__ bias2,
               float* __restrict__ Cout, int ldc)
{
    constexpr int n1 = K1 >> 6;
    constexpr int nT = (K1 + K2) >> 6;
    __shared__ __attribute__((aligned(16))) __hip_bfloat16 As[2][16][LSTRIDE];
    __shared__ __attribute__((aligned(16))) __hip_bfloat16 Ws[2][32][LSTRIDE];
    __shared__ float red[2][16][17];
    const int tid = threadIdx.x;
    const int lane = tid & 63;
    const int wave = tid >> 6;
    const int quad = lane >> 4, l15 = lane & 15;
    const int cf = wave & 1;   // col frag (16 cols each)
    const int kh = wave >> 1;  // k-half (32 each within BK=64)
    const int m_base = blockIdx.y * 16;
    const int n_base = blockIdx.x * 32;

    // staging: A 16x64 = 1024 el -> 4/thr (1 f4); W 32x64 = 2048 -> 8/thr (2 f4)
    const int arow = tid >> 4, acol = (tid & 15) << 2;
    const int wrow = tid >> 3, wcol = (tid & 7) << 3;

    const float* baseA1 = A1 + (size_t)(m_base + arow) * K1 + acol;
    const float* baseA2 = A2 + (size_t)(m_base + arow) * K2 + acol;
    const float* baseW1 = W1 + (size_t)(n_base + wrow) * ldw1 + ofs1 + wcol;
    const float* baseW2 = W2 + (size_t)(n_base + wrow) * ldw2 + ofs2 + wcol;

    float4 pa, pw0, pw1;
    auto issue = [&](int tt) {
        const float *ap, *wp;
        if (tt < n1) { ap = baseA1 + (tt << 6);        wp = baseW1 + (tt << 6); }
        else         { ap = baseA2 + ((tt - n1) << 6); wp = baseW2 + ((tt - n1) << 6); }
        pa  = *(const float4*)(ap);
        pw0 = *(const float4*)(wp);
        pw1 = *(const float4*)(wp + 4);
    };
    issue(0);

    floatx4 acc = (floatx4){0.f, 0.f, 0.f, 0.f};
    for (int t = 0; t < nT; t++) {
        const int buf = t & 1;
        *(short4v*)(&As[buf][arow][acol]) = cvt4v(pa);
        *(short8*)(&Ws[buf][wrow][wcol])  = cvt8v(pw0, pw1);
        __syncthreads();
        if (t + 1 < nT) issue(t + 1);
        short8 af = *(const short8*)(&As[buf][l15][kh * 32 + quad * 8]);
        short8 bf = *(const short8*)(&Ws[buf][cf * 16 + l15][kh * 32 + quad * 8]);
        acc = __builtin_amdgcn_mfma_f32_16x16x32_bf16(af, bf, acc, 0, 0, 0);
    }

    // k-split reduction: kh=1 waves stash, kh=0 waves combine + epilogue.
    if (kh == 1) {
#pragma unroll
        for (int r = 0; r < 4; r++) red[cf][l15][quad * 4 + r] = acc[r];
    }
    __syncthreads();
    if (kh == 0) {
        const int col = n_base + cf * 16 + l15;
        float bsum = bias1[col] + (bias2 ? bias2[col] : 0.f);
#pragma unroll
        for (int r = 0; r < 4; r++) {
            const int row = m_base + quad * 4 + r;
            float v = acc[r] + red[cf][l15][quad * 4 + r] + bsum;
            if (RELU) v = fmaxf(v, 0.f);
            Cout[(size_t)row * ldc + col] = v;
        }
    }
}

// ---------------------------------------------------------------------------
// Fused LSTM layer v2: gates = A1@Wih^T + A2@Whh^T + bih + bhh, cell fused.
// 512 thr = 8 waves, BM=128 (wave = 16-row m-frag), Wr=64 (16 h x 4 gates),
// BK=64. grid (128, 2) = 256 blocks = 1/CU.
// W duplication 2x (was 4x); A-slice per m-half = 1.5-2 MB.
// XCD remap: XCDs 0-3 own m-half 0, XCDs 4-7 own m-half 1, so each XCD's
// unique A working set fits its 4 MB L2 (A re-reads become L2 hits instead
// of LLC traffic); x contiguous per XCD for contiguous W streaming.
// Single barrier per K-tile (double-buffered LDS) + 2-deep register
// prefetch with NAMED sets (compile-time indexing, no scratch).
// ---------------------------------------------------------------------------
template<int K1>
__global__ __launch_bounds__(512)
void lstm_fused(const float* __restrict__ A1,
                const float* __restrict__ Wih,
                const float* __restrict__ A2,   // h_prev [256,2048]
                const float* __restrict__ Whh,  // [8192,2048]
                const float* __restrict__ bih,
                const float* __restrict__ bhh,
                const float* __restrict__ c0,
                float* __restrict__ h_out,
                float* __restrict__ c_out)
{
    constexpr int n1 = K1 >> 6;
    constexpr int nT = n1 + (HH >> 6);          // 48 (l0) or 64 (l1), even
    __shared__ __attribute__((aligned(16))) __hip_bfloat16 As[2][128][LSTRIDE];
    __shared__ __attribute__((aligned(16))) __hip_bfloat16 Ws[2][64][LSTRIDE];
    const int tid = threadIdx.x;
    const int lane = tid & 63;
    const int wave = tid >> 6;                  // m-frag 0..7
    const int quad = lane >> 4, l15 = lane & 15;

    // XCD-aware remap of the 256 blocks (gridDim = (128,2), x-major linear).
    const int L    = blockIdx.x + (blockIdx.y << 7);
    const int xcd  = L & 7;
    const int slot = L >> 3;                    // 0..31
    const int by   = xcd >> 2;                  // m-half per XCD group
    const int bx   = ((xcd & 3) << 5) + slot;   // 0..127, contiguous per XCD
    const int m_base = by * 128;
    const int n_base = bx * 16;                 // h-col base

    // A staging: 128x64 fp32 -> 16 floats/thr (4 f4). W: 64x64 -> 8/thr (2 f4).
    const int arow = tid >> 2, acol = (tid & 3) << 4;
    const int wrow = tid >> 3, wcol = (tid & 7) << 3;
    // Ws row r: gate = r>>4, h-col = n_base + (r&15)
    const int grow = (wrow >> 4) * HH + n_base + (wrow & 15);

    const float* baseA1 = A1 + (size_t)(m_base + arow) * K1 + acol;
    const float* baseA2 = A2 + (size_t)(m_base + arow) * HH + acol;
    const float* baseW1 = Wih + (size_t)grow * K1 + wcol;
    const float* baseW2 = Whh + (size_t)grow * HH + wcol;

    float4 paA[4], pwA[2], paB[4], pwB[2];
    auto issue = [&](int tt, float4 (&pa)[4], float4 (&pw)[2]) {
        const float *ap, *wp;
        if (tt < n1) { ap = baseA1 + (tt << 6);        wp = baseW1 + (tt << 6); }
        else         { ap = baseA2 + ((tt - n1) << 6); wp = baseW2 + ((tt - n1) << 6); }
#pragma unroll
        for (int j = 0; j < 4; j++) pa[j] = *(const float4*)(ap + (j << 2));
#pragma unroll
        for (int j = 0; j < 2; j++) pw[j] = *(const float4*)(wp + (j << 2));
    };
    issue(0, paA, pwA);
    issue(1, paB, pwB);

    floatx4 acc[4];
#pragma unroll
    for (int g = 0; g < 4; g++) acc[g] = (floatx4){0.f, 0.f, 0.f, 0.f};

    auto compute = [&](int buf) {
#pragma unroll
        for (int k = 0; k < 2; k++) {
            short8 af = *(const short8*)(&As[buf][wave * 16 + l15][k * 32 + quad * 8]);
#pragma unroll
            for (int g = 0; g < 4; g++) {
                short8 bf = *(const short8*)(&Ws[buf][g * 16 + l15][k * 32 + quad * 8]);
                acc[g] = __builtin_amdgcn_mfma_f32_16x16x32_bf16(af, bf, acc[g], 0, 0, 0);
            }
        }
    };

    // Single barrier per tile: write buf -> barrier -> MFMA buf.
    // Safe: a wave reaches barrier(t+1) only after compute(t), so writes of
    // tile t+2 (same buf as t, after barrier(t+1)) cannot race compute(t).
    for (int t = 0; t < nT; t += 2) {
        // even tile -> buf 0, set A
        *(short8*)(&As[0][arow][acol])     = cvt8v(paA[0], paA[1]);
        *(short8*)(&As[0][arow][acol + 8]) = cvt8v(paA[2], paA[3]);
        *(short8*)(&Ws[0][wrow][wcol])     = cvt8v(pwA[0], pwA[1]);
        if (t + 2 < nT) issue(t + 2, paA, pwA);
        __syncthreads();
        compute(0);
        // odd tile -> buf 1, set B
        *(short8*)(&As[1][arow][acol])     = cvt8v(paB[0], paB[1]);
        *(short8*)(&As[1][arow][acol + 8]) = cvt8v(paB[2], paB[3]);
        *(short8*)(&Ws[1][wrow][wcol])     = cvt8v(pwB[0], pwB[1]);
        if (t + 3 < nT) issue(t + 3, paB, pwB);
        __syncthreads();
        compute(1);
    }

    // epilogue: lane holds i,f,g,o for (row,col); fused LSTM cell, fp32 out.
    const int col = n_base + l15;
    float bsum[4];
#pragma unroll
    for (int g = 0; g < 4; g++)
        bsum[g] = bih[g * HH + col] + bhh[g * HH + col];

#pragma unroll
    for (int r = 0; r < 4; r++) {
        const int row = m_base + wave * 16 + quad * 4 + r;
        const size_t idx = (size_t)row * HH + col;
        float gi = acc[0][r] + bsum[0];
        float gf = acc[1][r] + bsum[1];
        float gg = acc[2][r] + bsum[2];
        float go = acc[3][r] + bsum[3];
        float c0v = c0[idx];
        float cn = sigf(gf) * c0v + sigf(gi) * tanhf(gg);
        float hn = sigf(go) * tanhf(cn);
        h_out[idx] = hn;
        c_out[idx] = cn;
    }
}

// ---------------------------------------------------------------------------
extern "C" void kernel_launch(void* const* d_in, const int* in_sizes, int n_in,
                              void* d_out, int out_size, void* d_ws, size_t ws_size,
                              hipStream_t stream) {
    const float* x      = (const float*)d_in[0];
    const float* h0     = (const float*)d_in[1];
    const float* c0     = (const float*)d_in[2];
    const float* enc    = (const float*)d_in[3];
    const float* attn_W = (const float*)d_in[4];
    const float* attn_b = (const float*)d_in[5];
    const float* comb_W = (const float*)d_in[6];
    const float* comb_b = (const float*)d_in[7];
    const float* Wih0   = (const float*)d_in[8];
    const float* Whh0   = (const float*)d_in[9];
    const float* bih0   = (const float*)d_in[10];
    const float* bhh0   = (const float*)d_in[11];
    const float* Wih1   = (const float*)d_in[12];
    const float* Whh1   = (const float*)d_in[13];
    const float* bih1   = (const float*)d_in[14];
    const float* bhh1   = (const float*)d_in[15];
    const float* out_W  = (const float*)d_in[16];
    const float* out_b  = (const float*)d_in[17];

    float* pred = (float*)d_out;
    float* h1   = pred + 262144;
    float* h2   = h1 + 524288;
    float* c1   = h2 + 524288;
    float* c2   = c1 + 524288;
    const float* h0_l0 = h0;
    const float* h0_l1 = h0 + 524288;
    const float* c0_l0 = c0;
    const float* c0_l1 = c0 + 524288;

    // Scratch aliased inside d_out (zero d_ws usage):
    //   xin aliases pred       (read step 4; pred written step 6)
    //   attn_out aliases c2    (read step 3; c2 written step 5)
    //   wts aliases c1 start   (read step 2; c1 written step 4)
    float* xin      = pred;
    float* attn_out = c2;
    float* wts      = c1;

    // 1. attention logits + softmax
    attn_logits<<<dim3(BB), dim3(256), 0, stream>>>(x, h0_l0, attn_W, attn_b, wts);

    // 2. attention apply
    attn_apply<<<dim3(BB * 2), dim3(256), 0, stream>>>(enc, wts, attn_out);

    // 3. comb: xin = relu([x0|attn] @ comb_W^T + comb_b)  N=1024, K=1024+2048
    gemm_dual<OO, HH, true><<<dim3(OO / 32, BB / 16), dim3(256), 0, stream>>>(
        x, comb_W, OO + HH, 0,
        attn_out, comb_W, OO + HH, OO,
        comb_b, nullptr, xin, OO);

    // 4. LSTM layer 0 -> h1, c1
    lstm_fused<OO><<<dim3(HH / 16, BB / 128), dim3(512), 0, stream>>>(
        xin, Wih0, h0_l0, Whh0, bih0, bhh0, c0_l0, h1, c1);

    // 5. LSTM layer 1 -> h2, c2
    lstm_fused<HH><<<dim3(HH / 16, BB / 128), dim3(512), 0, stream>>>(
        h1, Wih1, h0_l1, Whh1, bih1, bhh1, c0_l1, h2, c2);

    // 6. prediction = h2 @ out_W^T + out_b  N=1024, K=2048
    gemm_dual<HH, 0, false><<<dim3(OO / 32, BB / 16), dim3(256), 0, stream>>>(
        h2, out_W, HH, 0,
        h2, out_W, HH, 0,
        out_b, nullptr, pred, OO);
}

// Round 2
// 398.835 us; speedup vs baseline: 1.1627x; 1.0147x over previous
//
#include <hip/hip_runtime.h>
#include <hip/hip_bf16.h>

typedef short short8 __attribute__((ext_vector_type(8)));
typedef short short4v __attribute__((ext_vector_type(4)));
typedef float floatx4 __attribute__((ext_vector_type(4)));

#define BB 256
#define OO 1024
#define HH 2048
#define SS 12
#define LSTRIDE 72   // 64 + 8 pad elems; 144 B rows, 16B-aligned (gemm_dual only)

__device__ __forceinline__ __hip_bfloat16 f2b(float x) { return __float2bfloat16(x); }
__device__ __forceinline__ float sigf(float x) { return 1.0f / (1.0f + expf(-x)); }

__device__ __forceinline__ short8 cvt8v(float4 lo, float4 hi) {
    union { short8 s; __hip_bfloat16 h[8]; } u;
    u.h[0] = f2b(lo.x); u.h[1] = f2b(lo.y); u.h[2] = f2b(lo.z); u.h[3] = f2b(lo.w);
    u.h[4] = f2b(hi.x); u.h[5] = f2b(hi.y); u.h[6] = f2b(hi.z); u.h[7] = f2b(hi.w);
    return u.s;
}
__device__ __forceinline__ short4v cvt4v(float4 v) {
    union { short4v s; __hip_bfloat16 h[4]; } u;
    u.h[0] = f2b(v.x); u.h[1] = f2b(v.y); u.h[2] = f2b(v.z); u.h[3] = f2b(v.w);
    return u.s;
}

// ---------------------------------------------------------------------------
// Attention phase 1: logits + softmax -> wts[256][12]
// ---------------------------------------------------------------------------
__global__ __launch_bounds__(256)
void attn_logits(const float* __restrict__ x0,
                 const float* __restrict__ h00,
                 const float* __restrict__ attn_W,
                 const float* __restrict__ attn_b,
                 float* __restrict__ wts)
{
    const int b = blockIdx.x;
    const int tid = threadIdx.x;
    const int lane = tid & 63;
    const int wave = tid >> 6;

    float part[SS];
#pragma unroll
    for (int s = 0; s < SS; s++) part[s] = 0.f;

#pragma unroll
    for (int k = 0; k < 3; k++) {
        const int c = tid + (k << 8);
        float4 v = (k == 0) ? *(const float4*)(x0 + (size_t)b * OO + (c << 2))
                            : *(const float4*)(h00 + (size_t)b * HH + ((c - 256) << 2));
#pragma unroll
        for (int s = 0; s < SS; s++) {
            float4 w4 = *(const float4*)(attn_W + (size_t)s * (OO + HH) + (c << 2));
            part[s] += v.x * w4.x + v.y * w4.y + v.z * w4.z + v.w * w4.w;
        }
    }
#pragma unroll
    for (int s = 0; s < SS; s++) {
#pragma unroll
        for (int off = 32; off > 0; off >>= 1)
            part[s] += __shfl_down(part[s], off);
    }
    __shared__ float red[4][SS];
    if (lane == 0) {
#pragma unroll
        for (int s = 0; s < SS; s++) red[wave][s] = part[s];
    }
    __syncthreads();
    if (tid == 0) {
        float logits[SS];
        float mx = -1e30f;
        for (int s = 0; s < SS; s++) {
            logits[s] = red[0][s] + red[1][s] + red[2][s] + red[3][s] + attn_b[s];
            mx = fmaxf(mx, logits[s]);
        }
        float sum = 0.f;
        for (int s = 0; s < SS; s++) { logits[s] = expf(logits[s] - mx); sum += logits[s]; }
        float inv = 1.0f / sum;
        for (int s = 0; s < SS; s++) wts[b * SS + s] = logits[s] * inv;
    }
}

// ---------------------------------------------------------------------------
// Attention phase 2: attn_out[b,h] = sum_s wts[b,s]*enc[s,b,h]
// ---------------------------------------------------------------------------
__global__ __launch_bounds__(256)
void attn_apply(const float* __restrict__ enc,
                const float* __restrict__ wts,
                float* __restrict__ attn_out)
{
    const int b = blockIdx.x >> 1;
    const int half = blockIdx.x & 1;
    const int tid = threadIdx.x;
    __shared__ float w[SS];
    if (tid < SS) w[tid] = wts[b * SS + tid];
    __syncthreads();
    const int h = (half << 10) + (tid << 2);
    float4 a = {0.f, 0.f, 0.f, 0.f};
#pragma unroll
    for (int s = 0; s < SS; s++) {
        float4 e = *(const float4*)(enc + ((size_t)(s * BB + b) * HH) + h);
        float ws = w[s];
        a.x += ws * e.x; a.y += ws * e.y; a.z += ws * e.z; a.w += ws * e.w;
    }
    *(float4*)(attn_out + (size_t)b * HH + h) = a;
}

// ---------------------------------------------------------------------------
// Dual-segment GEMM (comb / out projection) — unchanged this round.
// ---------------------------------------------------------------------------
template<int K1, int K2, bool RELU>
__global__ __launch_bounds__(256)
void gemm_dual(const float* __restrict__ A1,
               const float* __restrict__ W1, int ldw1, int ofs1,
               const float* __restrict__ A2,
               const float* __restrict__ W2, int ldw2, int ofs2,
               const float* __restrict__ bias1,
               const float* __restrict__ bias2,
               float* __restrict__ Cout, int ldc)
{
    constexpr int n1 = K1 >> 6;
    constexpr int nT = (K1 + K2) >> 6;
    __shared__ __attribute__((aligned(16))) __hip_bfloat16 As[2][16][LSTRIDE];
    __shared__ __attribute__((aligned(16))) __hip_bfloat16 Ws[2][32][LSTRIDE];
    __shared__ float red[2][16][17];
    const int tid = threadIdx.x;
    const int lane = tid & 63;
    const int wave = tid >> 6;
    const int quad = lane >> 4, l15 = lane & 15;
    const int cf = wave & 1;   // col frag (16 cols each)
    const int kh = wave >> 1;  // k-half (32 each within BK=64)
    const int m_base = blockIdx.y * 16;
    const int n_base = blockIdx.x * 32;

    const int arow = tid >> 4, acol = (tid & 15) << 2;
    const int wrow = tid >> 3, wcol = (tid & 7) << 3;

    const float* baseA1 = A1 + (size_t)(m_base + arow) * K1 + acol;
    const float* baseA2 = A2 + (size_t)(m_base + arow) * K2 + acol;
    const float* baseW1 = W1 + (size_t)(n_base + wrow) * ldw1 + ofs1 + wcol;
    const float* baseW2 = W2 + (size_t)(n_base + wrow) * ldw2 + ofs2 + wcol;

    float4 pa, pw0, pw1;
    auto issue = [&](int tt) {
        const float *ap, *wp;
        if (tt < n1) { ap = baseA1 + (tt << 6);        wp = baseW1 + (tt << 6); }
        else         { ap = baseA2 + ((tt - n1) << 6); wp = baseW2 + ((tt - n1) << 6); }
        pa  = *(const float4*)(ap);
        pw0 = *(const float4*)(wp);
        pw1 = *(const float4*)(wp + 4);
    };
    issue(0);

    floatx4 acc = (floatx4){0.f, 0.f, 0.f, 0.f};
    for (int t = 0; t < nT; t++) {
        const int buf = t & 1;
        *(short4v*)(&As[buf][arow][acol]) = cvt4v(pa);
        *(short8*)(&Ws[buf][wrow][wcol])  = cvt8v(pw0, pw1);
        __syncthreads();
        if (t + 1 < nT) issue(t + 1);
        short8 af = *(const short8*)(&As[buf][l15][kh * 32 + quad * 8]);
        short8 bf = *(const short8*)(&Ws[buf][cf * 16 + l15][kh * 32 + quad * 8]);
        acc = __builtin_amdgcn_mfma_f32_16x16x32_bf16(af, bf, acc, 0, 0, 0);
    }

    if (kh == 1) {
#pragma unroll
        for (int r = 0; r < 4; r++) red[cf][l15][quad * 4 + r] = acc[r];
    }
    __syncthreads();
    if (kh == 0) {
        const int col = n_base + cf * 16 + l15;
        float bsum = bias1[col] + (bias2 ? bias2[col] : 0.f);
#pragma unroll
        for (int r = 0; r < 4; r++) {
            const int row = m_base + quad * 4 + r;
            float v = acc[r] + red[cf][l15][quad * 4 + r] + bsum;
            if (RELU) v = fmaxf(v, 0.f);
            Cout[(size_t)row * ldc + col] = v;
        }
    }
}

// ---------------------------------------------------------------------------
// LSTM gates v3: split-K partial GEMM, traffic-minimal tiling.
// gates_partial[ks] = A[:, kslice] @ W[:, kslice]^T   (W rows = i|f|g|o gates)
// BM=256 (all rows), BN_h=32 (128 W-rows), BK=32, 4-way split-K.
// grid (64 n-blocks, 4 k-quarters) = 256 blocks, 512 thr = 8 waves.
// Traffic: l1 = 256*(1MB A + 0.5MB W) + 32MB partials = 416 MB (was 786).
// XCD remap: XCD pair g owns k-quarter g>>1 -> per-XCD unique A = 1 MB,
// fits 4MB L2 alongside W stream -> A re-reads become L2 hits.
// LDS: 48 KB, XOR-swizzled (byte ^= (row&7)<<4) -> conflict-free b128 r/w
// (replaces pad-72 layout that had 8-way conflicts, 5.24M cyc/dispatch).
// 1 barrier/tile dbuf + 2-deep named register prefetch.
// ---------------------------------------------------------------------------
#define A_BUF_BYTES 16384              // 256 rows * 64 B
#define W_BUF_BYTES 8192               // 128 rows * 64 B
__device__ __forceinline__ int swzA(int buf, int row, int c8) {
    return (buf << 14) + ((((row << 6) | (c8 << 4))) ^ ((row & 7) << 4));
}
__device__ __forceinline__ int swzW(int buf, int row, int c8) {
    return 2 * A_BUF_BYTES + (buf << 13) + ((((row << 6) | (c8 << 4))) ^ ((row & 7) << 4));
}

template<int K1>
__global__ __launch_bounds__(512)
void lstm_gates(const float* __restrict__ A1,   // [256, K1]
                const float* __restrict__ Wih,  // [8192, K1]
                const float* __restrict__ A2,   // h_prev [256, 2048]
                const float* __restrict__ Whh,  // [8192, 2048]
                float* __restrict__ P)          // partials [4][256][8192]
{
    constexpr int KTOT = K1 + HH;
    constexpr int KPER = KTOT / 4;
    constexpr int NT = KPER / 32;               // 32 (l1) / 24 (l0), even
    __shared__ __attribute__((aligned(128))) unsigned char lds[2 * A_BUF_BYTES + 2 * W_BUF_BYTES];

    const int tid = threadIdx.x;
    const int lane = tid & 63;
    const int wave = tid >> 6;                  // 0..7: rows 32w..32w+31
    const int quad = lane >> 4, l15 = lane & 15;

    // XCD remap: L = bx + 64*ks_orig; xcd = L&7 owns (ks = xcd>>1, 32 n-slots)
    const int L    = blockIdx.x + (blockIdx.y << 6);
    const int xcd  = L & 7;
    const int slot = L >> 3;                    // 0..31
    const int ks   = xcd >> 1;                  // k-quarter
    const int nb   = ((xcd & 1) << 5) | slot;   // 0..63
    const int n_base = nb << 5;                 // h-col base (32 cols)
    const int k0 = ks * KPER;

    // staging: A 256x32 -> 16 el/thr (4 f4, 2 b128 writes); W 128x32 -> 8 el/thr
    const int arow = tid >> 1;                  // 0..255
    const int ac8  = (tid & 1) << 1;            // A col-chunk-of-8 base (0 or 2)
    const int wrow = tid >> 2;                  // 0..127
    const int wc8  = tid & 3;                   // W col-chunk-of-8
    // W row r: gate = r>>5, h-col = n_base + (r&31)
    const int grow = (wrow >> 5) * HH + n_base + (wrow & 31);

    const float* bA1 = A1 + (size_t)arow * K1 + (ac8 << 3);
    const float* bA2 = A2 + (size_t)arow * HH + (ac8 << 3);
    const float* bW1 = Wih + (size_t)grow * K1 + (wc8 << 3);
    const float* bW2 = Whh + (size_t)grow * HH + (wc8 << 3);

    float4 paA[4], pwA[2], paB[4], pwB[2];
    auto issue = [&](int tt, float4 (&pa)[4], float4 (&pw)[2]) {
        const int gk = k0 + (tt << 5);
        const float *ap, *wp;
        if (gk < K1) { ap = bA1 + gk;        wp = bW1 + gk; }
        else         { ap = bA2 + (gk - K1); wp = bW2 + (gk - K1); }
#pragma unroll
        for (int j = 0; j < 4; j++) pa[j] = *(const float4*)(ap + (j << 2));
#pragma unroll
        for (int j = 0; j < 2; j++) pw[j] = *(const float4*)(wp + (j << 2));
    };
    issue(0, paA, pwA);
    issue(1, paB, pwB);

    floatx4 acc[2][4][2];                       // [m-frag][gate][n-frag]
#pragma unroll
    for (int mf = 0; mf < 2; mf++)
#pragma unroll
        for (int g = 0; g < 4; g++)
#pragma unroll
            for (int nf = 0; nf < 2; nf++)
                acc[mf][g][nf] = (floatx4){0.f, 0.f, 0.f, 0.f};

    auto store_tile = [&](int buf, float4 (&pa)[4], float4 (&pw)[2]) {
        *(short8*)(lds + swzA(buf, arow, ac8))     = cvt8v(pa[0], pa[1]);
        *(short8*)(lds + swzA(buf, arow, ac8 | 1)) = cvt8v(pa[2], pa[3]);
        *(short8*)(lds + swzW(buf, wrow, wc8))     = cvt8v(pw[0], pw[1]);
    };
    auto compute = [&](int buf) {
        short8 af[2];
#pragma unroll
        for (int mf = 0; mf < 2; mf++)
            af[mf] = *(const short8*)(lds + swzA(buf, (wave << 5) + (mf << 4) + l15, quad));
#pragma unroll
        for (int g = 0; g < 4; g++)
#pragma unroll
            for (int nf = 0; nf < 2; nf++) {
                short8 bf = *(const short8*)(lds + swzW(buf, (g << 5) + (nf << 4) + l15, quad));
                acc[0][g][nf] = __builtin_amdgcn_mfma_f32_16x16x32_bf16(af[0], bf, acc[0][g][nf], 0, 0, 0);
                acc[1][g][nf] = __builtin_amdgcn_mfma_f32_16x16x32_bf16(af[1], bf, acc[1][g][nf], 0, 0, 0);
            }
    };

    // 1 barrier/tile: write buf -> barrier -> MFMA buf (see r1 safety argument)
    for (int t = 0; t < NT; t += 2) {
        store_tile(0, paA, pwA);
        if (t + 2 < NT) issue(t + 2, paA, pwA);
        __syncthreads();
        compute(0);
        store_tile(1, paB, pwB);
        if (t + 3 < NT) issue(t + 3, paB, pwB);
        __syncthreads();
        compute(1);
    }

    // write partial gate sums: P[ks][row][g*2048 + col]
    float* Pk = P + (size_t)ks * (256 * 8192);
#pragma unroll
    for (int mf = 0; mf < 2; mf++)
#pragma unroll
        for (int g = 0; g < 4; g++)
#pragma unroll
            for (int nf = 0; nf < 2; nf++) {
                const int col = n_base + (nf << 4) + l15;
#pragma unroll
                for (int r = 0; r < 4; r++) {
                    const int row = (wave << 5) + (mf << 4) + (quad << 2) + r;
                    Pk[(size_t)row * 8192 + g * HH + col] = acc[mf][g][nf][r];
                }
            }
}

// ---------------------------------------------------------------------------
// LSTM cell epilogue: sum 4 partials + biases, apply cell, write h/c.
// 256 blocks x 512 thr; each thread one (row, 4 cols). ~38 MB traffic.
// ---------------------------------------------------------------------------
__global__ __launch_bounds__(512)
void lstm_cell(const float* __restrict__ P,
               const float* __restrict__ bih,
               const float* __restrict__ bhh,
               const float* __restrict__ c0,
               float* __restrict__ h_out,
               float* __restrict__ c_out)
{
    const int gid = blockIdx.x * 512 + threadIdx.x;
    const int row = gid >> 9;
    const int col = (gid & 511) << 2;

    float4 gate[4];
#pragma unroll
    for (int g = 0; g < 4; g++) {
        const size_t base = (size_t)row * 8192 + g * HH + col;
        float4 s = *(const float4*)(P + base);
#pragma unroll
        for (int k = 1; k < 4; k++) {
            float4 v = *(const float4*)(P + (size_t)k * (256 * 8192) + base);
            s.x += v.x; s.y += v.y; s.z += v.z; s.w += v.w;
        }
        float4 b1 = *(const float4*)(bih + g * HH + col);
        float4 b2 = *(const float4*)(bhh + g * HH + col);
        s.x += b1.x + b2.x; s.y += b1.y + b2.y; s.z += b1.z + b2.z; s.w += b1.w + b2.w;
        gate[g] = s;
    }
    const size_t idx = (size_t)row * HH + col;
    float4 cv = *(const float4*)(c0 + idx);
    float4 hn, cn;
    {
        float c_ = sigf(gate[1].x) * cv.x + sigf(gate[0].x) * tanhf(gate[2].x);
        cn.x = c_; hn.x = sigf(gate[3].x) * tanhf(c_);
        c_ = sigf(gate[1].y) * cv.y + sigf(gate[0].y) * tanhf(gate[2].y);
        cn.y = c_; hn.y = sigf(gate[3].y) * tanhf(c_);
        c_ = sigf(gate[1].z) * cv.z + sigf(gate[0].z) * tanhf(gate[2].z);
        cn.z = c_; hn.z = sigf(gate[3].z) * tanhf(c_);
        c_ = sigf(gate[1].w) * cv.w + sigf(gate[0].w) * tanhf(gate[2].w);
        cn.w = c_; hn.w = sigf(gate[3].w) * tanhf(c_);
    }
    *(float4*)(h_out + idx) = hn;
    *(float4*)(c_out + idx) = cn;
}

// ---------------------------------------------------------------------------
extern "C" void kernel_launch(void* const* d_in, const int* in_sizes, int n_in,
                              void* d_out, int out_size, void* d_ws, size_t ws_size,
                              hipStream_t stream) {
    const float* x      = (const float*)d_in[0];
    const float* h0     = (const float*)d_in[1];
    const float* c0     = (const float*)d_in[2];
    const float* enc    = (const float*)d_in[3];
    const float* attn_W = (const float*)d_in[4];
    const float* attn_b = (const float*)d_in[5];
    const float* comb_W = (const float*)d_in[6];
    const float* comb_b = (const float*)d_in[7];
    const float* Wih0   = (const float*)d_in[8];
    const float* Whh0   = (const float*)d_in[9];
    const float* bih0   = (const float*)d_in[10];
    const float* bhh0   = (const float*)d_in[11];
    const float* Wih1   = (const float*)d_in[12];
    const float* Whh1   = (const float*)d_in[13];
    const float* bih1   = (const float*)d_in[14];
    const float* bhh1   = (const float*)d_in[15];
    const float* out_W  = (const float*)d_in[16];
    const float* out_b  = (const float*)d_in[17];

    float* pred = (float*)d_out;
    float* h1   = pred + 262144;
    float* h2   = h1 + 524288;
    float* c1   = h2 + 524288;
    float* c2   = c1 + 524288;
    const float* h0_l0 = h0;
    const float* h0_l1 = h0 + 524288;
    const float* c0_l0 = c0;
    const float* c0_l1 = c0 + 524288;

    // Scratch aliased inside d_out (as before):
    //   xin aliases pred, attn_out aliases c2, wts aliases c1.
    // Split-K partials: 4 x [256][8192] fp32 = 32 MB in d_ws.
    float* xin      = pred;
    float* attn_out = c2;
    float* wts      = c1;
    float* P        = (float*)d_ws;

    // 1. attention logits + softmax
    attn_logits<<<dim3(BB), dim3(256), 0, stream>>>(x, h0_l0, attn_W, attn_b, wts);

    // 2. attention apply
    attn_apply<<<dim3(BB * 2), dim3(256), 0, stream>>>(enc, wts, attn_out);

    // 3. comb: xin = relu([x0|attn] @ comb_W^T + comb_b)  N=1024, K=1024+2048
    gemm_dual<OO, HH, true><<<dim3(OO / 32, BB / 16), dim3(256), 0, stream>>>(
        x, comb_W, OO + HH, 0,
        attn_out, comb_W, OO + HH, OO,
        comb_b, nullptr, xin, OO);

    // 4. LSTM layer 0: split-K gates + cell epilogue -> h1, c1
    lstm_gates<OO><<<dim3(64, 4), dim3(512), 0, stream>>>(xin, Wih0, h0_l0, Whh0, P);
    lstm_cell<<<dim3(256), dim3(512), 0, stream>>>(P, bih0, bhh0, c0_l0, h1, c1);

    // 5. LSTM layer 1: split-K gates + cell epilogue -> h2, c2
    lstm_gates<HH><<<dim3(64, 4), dim3(512), 0, stream>>>(h1, Wih1, h0_l1, Whh1, P);
    lstm_cell<<<dim3(256), dim3(512), 0, stream>>>(P, bih1, bhh1, c0_l1, h2, c2);

    // 6. prediction = h2 @ out_W^T + out_b  N=1024, K=2048
    gemm_dual<HH, 0, false><<<dim3(OO / 32, BB / 16), dim3(256), 0, stream>>>(
        h2, out_W, HH, 0,
        h2, out_W, HH, 0,
        out_b, nullptr, pred, OO);
}

// Round 3
// 364.747 us; speedup vs baseline: 1.2713x; 1.0935x over previous
//
#include <hip/hip_runtime.h>
#include <hip/hip_bf16.h>

typedef short short8 __attribute__((ext_vector_type(8)));
typedef short short4v __attribute__((ext_vector_type(4)));
typedef float floatx4 __attribute__((ext_vector_type(4)));

#define BB 256
#define OO 1024
#define HH 2048
#define SS 12

__device__ __forceinline__ __hip_bfloat16 f2b(float x) { return __float2bfloat16(x); }
__device__ __forceinline__ float sigf(float x) { return 1.0f / (1.0f + expf(-x)); }

__device__ __forceinline__ short8 cvt8v(float4 lo, float4 hi) {
    union { short8 s; __hip_bfloat16 h[8]; } u;
    u.h[0] = f2b(lo.x); u.h[1] = f2b(lo.y); u.h[2] = f2b(lo.z); u.h[3] = f2b(lo.w);
    u.h[4] = f2b(hi.x); u.h[5] = f2b(hi.y); u.h[6] = f2b(hi.z); u.h[7] = f2b(hi.w);
    return u.s;
}
__device__ __forceinline__ short4v cvt4v(float4 v) {
    union { short4v s; __hip_bfloat16 h[4]; } u;
    u.h[0] = f2b(v.x); u.h[1] = f2b(v.y); u.h[2] = f2b(v.z); u.h[3] = f2b(v.w);
    return u.s;
}

// Swizzled LDS byte offsets within a tile buffer of 64 B bf16 rows.
// XOR (row&7)<<4 spreads the column slots; verified bijective & conflict-free
// for 8-rows-per-instr b64 writes and 16-aligned-row b128 reads.
__device__ __forceinline__ int swz16(int row, int c16) {   // 16 B granule (reads)
    return ((row << 6) | (c16 << 4)) ^ ((row & 7) << 4);
}
__device__ __forceinline__ int swz8(int row, int c8) {     // 8 B granule (writes)
    return ((row << 6) | (c8 << 3)) ^ ((row & 7) << 4);
}

// ---------------------------------------------------------------------------
// Fused attention: logits + softmax + apply in one kernel.
// 256 blocks (one per batch row) x 512 thr.
// ---------------------------------------------------------------------------
__global__ __launch_bounds__(512)
void attn_fused(const float* __restrict__ x0,
                const float* __restrict__ h00,
                const float* __restrict__ enc,
                const float* __restrict__ attn_W,
                const float* __restrict__ attn_b,
                float* __restrict__ attn_out)
{
    const int b = blockIdx.x;
    const int tid = threadIdx.x;
    const int lane = tid & 63;
    const int wave = tid >> 6;

    float part[SS];
#pragma unroll
    for (int s = 0; s < SS; s++) part[s] = 0.f;

    // chunk c = tid (0..511): c<256 -> x0, else h00. Second pass c = tid+512
    // (waves 0-3 only): always h00.
    {
        float4 v = (tid < 256) ? *(const float4*)(x0 + (size_t)b * OO + (tid << 2))
                               : *(const float4*)(h00 + (size_t)b * HH + ((tid - 256) << 2));
#pragma unroll
        for (int s = 0; s < SS; s++) {
            float4 w4 = *(const float4*)(attn_W + (size_t)s * (OO + HH) + (tid << 2));
            part[s] += v.x * w4.x + v.y * w4.y + v.z * w4.z + v.w * w4.w;
        }
    }
    if (tid < 256) {
        float4 v = *(const float4*)(h00 + (size_t)b * HH + ((tid + 256) << 2));
#pragma unroll
        for (int s = 0; s < SS; s++) {
            float4 w4 = *(const float4*)(attn_W + (size_t)s * (OO + HH) + ((tid + 512) << 2));
            part[s] += v.x * w4.x + v.y * w4.y + v.z * w4.z + v.w * w4.w;
        }
    }
#pragma unroll
    for (int s = 0; s < SS; s++) {
#pragma unroll
        for (int off = 32; off > 0; off >>= 1)
            part[s] += __shfl_down(part[s], off);
    }
    __shared__ float red[8][SS];
    __shared__ float sw[SS];
    if (lane == 0) {
#pragma unroll
        for (int s = 0; s < SS; s++) red[wave][s] = part[s];
    }
    __syncthreads();
    if (tid == 0) {
        float logits[SS];
        float mx = -1e30f;
        for (int s = 0; s < SS; s++) {
            float v = attn_b[s];
            for (int w = 0; w < 8; w++) v += red[w][s];
            logits[s] = v;
            mx = fmaxf(mx, v);
        }
        float sum = 0.f;
        for (int s = 0; s < SS; s++) { logits[s] = expf(logits[s] - mx); sum += logits[s]; }
        float inv = 1.0f / sum;
        for (int s = 0; s < SS; s++) sw[s] = logits[s] * inv;
    }
    __syncthreads();

    // apply: each thread one float4 of the 2048-wide output row
    float4 a = {0.f, 0.f, 0.f, 0.f};
#pragma unroll
    for (int s = 0; s < SS; s++) {
        float4 e = *(const float4*)(enc + ((size_t)(s * BB + b) * HH) + (tid << 2));
        float ws = sw[s];
        a.x += ws * e.x; a.y += ws * e.y; a.z += ws * e.z; a.w += ws * e.w;
    }
    *(float4*)(attn_out + (size_t)b * HH + (tid << 2)) = a;
}

// ---------------------------------------------------------------------------
// LSTM gates v4: split-K partial GEMM, coalesced staging.
// P[ks] = A[:, kslice] @ W[:, kslice]^T  (W rows = i|f|g|o gates)
// BM=256, 128 W-rows (4 gates x 32 h-cols), BK=32, 4-way split-K.
// grid (64, 4) = 256 blocks, 512 thr = 8 waves as 4(m) x 2(n).
// Staging: 8 lanes per row (row = tid>>3 + 64j, 16B chunk = tid&7) ->
// every load instr = 16 dense line-accesses (was 64) -- fixes the
// L1/TA-throughput bound (2560 -> ~770 accesses/tile/CU).
// LDS 48 KB dbuf, XOR swizzle, 1 barrier/tile, 2-deep named prefetch.
// ---------------------------------------------------------------------------
template<int K1>
__global__ __launch_bounds__(512)
void lstm_gates(const float* __restrict__ A1,   // [256, K1]
                const float* __restrict__ Wih,  // [8192, K1]
                const float* __restrict__ A2,   // h_prev [256, 2048]
                const float* __restrict__ Whh,  // [8192, 2048]
                float* __restrict__ P)          // partials [4][256][8192]
{
    constexpr int KTOT = K1 + HH;
    constexpr int KPER = KTOT / 4;
    constexpr int NT = KPER / 32;               // 32 (l1) / 24 (l0), even
    // A bufs: [0,16K),[16K,32K); W bufs: [32K,40K),[40K,48K)
    __shared__ __attribute__((aligned(128))) unsigned char lds[49152];

    const int tid = threadIdx.x;
    const int lane = tid & 63;
    const int wave = tid >> 6;
    const int quad = lane >> 4, l15 = lane & 15;
    const int mi = wave >> 1;                   // 0..3: 64-row m-slice
    const int ni = wave & 1;                    // 0..1: 64-W-row n-slice

    // XCD remap: XCD pair owns a k-quarter; per-XCD unique A-slice = 1 MB.
    const int L    = blockIdx.x + (blockIdx.y << 6);
    const int xcd  = L & 7;
    const int slot = L >> 3;                    // 0..31
    const int ks   = xcd >> 1;
    const int nb   = ((xcd & 1) << 5) | slot;   // 0..63
    const int n_base = nb << 5;
    const int k0 = ks * KPER;

    // coalesced staging coords
    const int sr = tid >> 3;                    // 0..63
    const int sc = tid & 7;                     // 16B fp32 chunk / 8B bf16 chunk

    const float* bA1 = A1 + (size_t)sr * K1 + (sc << 2);
    const float* bA2 = A2 + (size_t)sr * HH + (sc << 2);
    // W LDS row r <-> global row (r>>5)*HH + n_base + (r&31); staged rows sr, sr+64
    const int gr0 = (sr >> 5) * HH + n_base + (sr & 31);
    const int gr1 = ((sr + 64) >> 5) * HH + n_base + ((sr + 64) & 31);
    const float* bW1_0 = Wih + (size_t)gr0 * K1 + (sc << 2);
    const float* bW1_1 = Wih + (size_t)gr1 * K1 + (sc << 2);
    const float* bW2_0 = Whh + (size_t)gr0 * HH + (sc << 2);
    const float* bW2_1 = Whh + (size_t)gr1 * HH + (sc << 2);

    float4 paA[4], pwA[2], paB[4], pwB[2];
    auto issue = [&](int tt, float4 (&pa)[4], float4 (&pw)[2]) {
        const int gk = k0 + (tt << 5);
        if (gk < K1) {
#pragma unroll
            for (int j = 0; j < 4; j++)
                pa[j] = *(const float4*)(bA1 + (size_t)(j << 6) * K1 + gk);
            pw[0] = *(const float4*)(bW1_0 + gk);
            pw[1] = *(const float4*)(bW1_1 + gk);
        } else {
            const int g2 = gk - K1;
#pragma unroll
            for (int j = 0; j < 4; j++)
                pa[j] = *(const float4*)(bA2 + (size_t)(j << 6) * HH + g2);
            pw[0] = *(const float4*)(bW2_0 + g2);
            pw[1] = *(const float4*)(bW2_1 + g2);
        }
    };
    issue(0, paA, pwA);
    issue(1, paB, pwB);

    floatx4 acc[4][4];                          // [m-frag][w-frag]
#pragma unroll
    for (int m = 0; m < 4; m++)
#pragma unroll
        for (int f = 0; f < 4; f++) acc[m][f] = (floatx4){0.f, 0.f, 0.f, 0.f};

    auto store_tile = [&](int half, float4 (&pa)[4], float4 (&pw)[2]) {
        unsigned char* Ab = lds + (half << 14);
        unsigned char* Wb = lds + 32768 + (half << 13);
#pragma unroll
        for (int j = 0; j < 4; j++)
            *(short4v*)(Ab + swz8(sr + (j << 6), sc)) = cvt4v(pa[j]);
        *(short4v*)(Wb + swz8(sr, sc))      = cvt4v(pw[0]);
        *(short4v*)(Wb + swz8(sr + 64, sc)) = cvt4v(pw[1]);
    };
    auto compute = [&](int half) {
        const unsigned char* Ab = lds + (half << 14);
        const unsigned char* Wb = lds + 32768 + (half << 13);
        short8 af[4], bf[4];
#pragma unroll
        for (int m = 0; m < 4; m++)
            af[m] = *(const short8*)(Ab + swz16((mi << 6) + (m << 4) + l15, quad));
#pragma unroll
        for (int f = 0; f < 4; f++)
            bf[f] = *(const short8*)(Wb + swz16((ni << 6) + (f << 4) + l15, quad));
#pragma unroll
        for (int m = 0; m < 4; m++)
#pragma unroll
            for (int f = 0; f < 4; f++)
                acc[m][f] = __builtin_amdgcn_mfma_f32_16x16x32_bf16(af[m], bf[f], acc[m][f], 0, 0, 0);
    };

    for (int t = 0; t < NT; t += 2) {
        store_tile(0, paA, pwA);
        if (t + 2 < NT) issue(t + 2, paA, pwA);
        __syncthreads();
        compute(0);
        store_tile(1, paB, pwB);
        if (t + 3 < NT) issue(t + 3, paB, pwB);
        __syncthreads();
        compute(1);
    }

    // P[ks][row][gate*2048 + col]
    float* Pk = P + (size_t)ks * (256 * 8192);
#pragma unroll
    for (int m = 0; m < 4; m++)
#pragma unroll
        for (int f = 0; f < 4; f++) {
            const int gate = (ni << 1) + (f >> 1);
            const int col  = n_base + ((f & 1) << 4) + l15;
#pragma unroll
            for (int r = 0; r < 4; r++) {
                const int row = (mi << 6) + (m << 4) + (quad << 2) + r;
                Pk[(size_t)row * 8192 + gate * HH + col] = acc[m][f][r];
            }
        }
}

// ---------------------------------------------------------------------------
// Split-K partial GEMM for comb / out: P[ks] = A[:, ks] @ W[:, ks]^T
// A = [A1 | A2] (K1 + rest), W single matrix [N, KTOT] (cols = global k).
// BM=256, BN=32, BK=32, 8-way split-K -> grid (32, 8) = 256 blocks.
// One XCD per k-slice: per-XCD working set (A 384-512 KB + W 1-2 MB) is
// L2-resident. Same coalesced staging / swizzle / schedule as lstm_gates.
// ---------------------------------------------------------------------------
template<int K1, int KTOT>
__global__ __launch_bounds__(512)
void gemm_part(const float* __restrict__ A1,
               const float* __restrict__ A2,
               const float* __restrict__ W,    // [1024, KTOT]
               float* __restrict__ P)          // [8][256][1024]
{
    constexpr int KPER = KTOT / 8;
    constexpr int NT = KPER / 32;               // 12 (comb) / 8 (out), even
    // A bufs: [0,16K),[16K,32K); W bufs: [32K,34K),[34K,36K)
    __shared__ __attribute__((aligned(128))) unsigned char lds[36864];

    const int tid = threadIdx.x;
    const int lane = tid & 63;
    const int wave = tid >> 6;
    const int quad = lane >> 4, l15 = lane & 15;
    const int mi = wave >> 1;                   // 0..3: 64-row m-slice
    const int ni = wave & 1;                    // 0..1: 16-col n-slice

    const int L    = blockIdx.x + (blockIdx.y << 5);
    const int xcd  = L & 7;
    const int ks   = xcd;                       // one XCD per k-slice
    const int nb   = L >> 3;                    // 0..31
    const int n_base = nb << 5;
    const int k0 = ks * KPER;

    const int sr = tid >> 3;                    // 0..63
    const int sc = tid & 7;

    const float* bA1 = A1 + (size_t)sr * K1 + (sc << 2);
    const float* bA2 = A2 + (size_t)sr * HH + (sc << 2);
    // W tile: 32 rows; threads 0..255 stage (wr = tid>>3, chunk tid&7)
    const float* bW = W + (size_t)(n_base + sr) * KTOT + (sc << 2);  // valid for tid<256

    float4 paA[4], paB[4];
    float4 pwA, pwB;
    auto issue = [&](int tt, float4 (&pa)[4], float4& pw) {
        const int gk = k0 + (tt << 5);
        if (gk < K1) {
#pragma unroll
            for (int j = 0; j < 4; j++)
                pa[j] = *(const float4*)(bA1 + (size_t)(j << 6) * K1 + gk);
        } else {
            const int g2 = gk - K1;
#pragma unroll
            for (int j = 0; j < 4; j++)
                pa[j] = *(const float4*)(bA2 + (size_t)(j << 6) * HH + g2);
        }
        if (tid < 256) pw = *(const float4*)(bW + gk);
    };
    issue(0, paA, pwA);
    issue(1, paB, pwB);

    floatx4 acc[4];
#pragma unroll
    for (int m = 0; m < 4; m++) acc[m] = (floatx4){0.f, 0.f, 0.f, 0.f};

    auto store_tile = [&](int half, float4 (&pa)[4], float4& pw) {
        unsigned char* Ab = lds + (half << 14);
        unsigned char* Wb = lds + 32768 + (half << 11);
#pragma unroll
        for (int j = 0; j < 4; j++)
            *(short4v*)(Ab + swz8(sr + (j << 6), sc)) = cvt4v(pa[j]);
        if (tid < 256)
            *(short4v*)(Wb + swz8(sr, sc)) = cvt4v(pw);   // sr = wr (0..31) for tid<256
    };
    auto compute = [&](int half) {
        const unsigned char* Ab = lds + (half << 14);
        const unsigned char* Wb = lds + 32768 + (half << 11);
        short8 bf = *(const short8*)(Wb + swz16((ni << 4) + l15, quad));
#pragma unroll
        for (int m = 0; m < 4; m++) {
            short8 af = *(const short8*)(Ab + swz16((mi << 6) + (m << 4) + l15, quad));
            acc[m] = __builtin_amdgcn_mfma_f32_16x16x32_bf16(af, bf, acc[m], 0, 0, 0);
        }
    };

    for (int t = 0; t < NT; t += 2) {
        store_tile(0, paA, pwA);
        if (t + 2 < NT) issue(t + 2, paA, pwA);
        __syncthreads();
        compute(0);
        store_tile(1, paB, pwB);
        if (t + 3 < NT) issue(t + 3, paB, pwB);
        __syncthreads();
        compute(1);
    }

    float* Pk = P + (size_t)ks * (256 * 1024);
    const int col = n_base + (ni << 4) + l15;
#pragma unroll
    for (int m = 0; m < 4; m++)
#pragma unroll
        for (int r = 0; r < 4; r++) {
            const int row = (mi << 6) + (m << 4) + (quad << 2) + r;
            Pk[(size_t)row * 1024 + col] = acc[m][r];
        }
}

// ---------------------------------------------------------------------------
// GEMM epilogue: out = [relu](sum_8 P[k] + bias). 256 blk x 256 thr x f4.
// ---------------------------------------------------------------------------
template<bool RELU>
__global__ __launch_bounds__(256)
void gemm_epi(const float* __restrict__ P,
              const float* __restrict__ bias,
              float* __restrict__ out)
{
    const int gid = blockIdx.x * 256 + threadIdx.x;   // 65536 f4 units
    const int row = gid >> 8;
    const int c4 = (gid & 255) << 2;
    const size_t base = (size_t)row * 1024 + c4;
    float4 s = *(const float4*)(P + base);
#pragma unroll
    for (int k = 1; k < 8; k++) {
        float4 v = *(const float4*)(P + (size_t)k * (256 * 1024) + base);
        s.x += v.x; s.y += v.y; s.z += v.z; s.w += v.w;
    }
    float4 b = *(const float4*)(bias + c4);
    s.x += b.x; s.y += b.y; s.z += b.z; s.w += b.w;
    if (RELU) {
        s.x = fmaxf(s.x, 0.f); s.y = fmaxf(s.y, 0.f);
        s.z = fmaxf(s.z, 0.f); s.w = fmaxf(s.w, 0.f);
    }
    *(float4*)(out + base) = s;
}

// ---------------------------------------------------------------------------
// LSTM cell epilogue: sum 4 partials + biases, apply cell, write h/c.
// ---------------------------------------------------------------------------
__global__ __launch_bounds__(512)
void lstm_cell(const float* __restrict__ P,
               const float* __restrict__ bih,
               const float* __restrict__ bhh,
               const float* __restrict__ c0,
               float* __restrict__ h_out,
               float* __restrict__ c_out)
{
    const int gid = blockIdx.x * 512 + threadIdx.x;
    const int row = gid >> 9;
    const int col = (gid & 511) << 2;

    float4 gate[4];
#pragma unroll
    for (int g = 0; g < 4; g++) {
        const size_t base = (size_t)row * 8192 + g * HH + col;
        float4 s = *(const float4*)(P + base);
#pragma unroll
        for (int k = 1; k < 4; k++) {
            float4 v = *(const float4*)(P + (size_t)k * (256 * 8192) + base);
            s.x += v.x; s.y += v.y; s.z += v.z; s.w += v.w;
        }
        float4 b1 = *(const float4*)(bih + g * HH + col);
        float4 b2 = *(const float4*)(bhh + g * HH + col);
        s.x += b1.x + b2.x; s.y += b1.y + b2.y; s.z += b1.z + b2.z; s.w += b1.w + b2.w;
        gate[g] = s;
    }
    const size_t idx = (size_t)row * HH + col;
    float4 cv = *(const float4*)(c0 + idx);
    float4 hn, cn;
    {
        float c_ = sigf(gate[1].x) * cv.x + sigf(gate[0].x) * tanhf(gate[2].x);
        cn.x = c_; hn.x = sigf(gate[3].x) * tanhf(c_);
        c_ = sigf(gate[1].y) * cv.y + sigf(gate[0].y) * tanhf(gate[2].y);
        cn.y = c_; hn.y = sigf(gate[3].y) * tanhf(c_);
        c_ = sigf(gate[1].z) * cv.z + sigf(gate[0].z) * tanhf(gate[2].z);
        cn.z = c_; hn.z = sigf(gate[3].z) * tanhf(c_);
        c_ = sigf(gate[1].w) * cv.w + sigf(gate[0].w) * tanhf(gate[2].w);
        cn.w = c_; hn.w = sigf(gate[3].w) * tanhf(c_);
    }
    *(float4*)(h_out + idx) = hn;
    *(float4*)(c_out + idx) = cn;
}

// ---------------------------------------------------------------------------
extern "C" void kernel_launch(void* const* d_in, const int* in_sizes, int n_in,
                              void* d_out, int out_size, void* d_ws, size_t ws_size,
                              hipStream_t stream) {
    const float* x      = (const float*)d_in[0];
    const float* h0     = (const float*)d_in[1];
    const float* c0     = (const float*)d_in[2];
    const float* enc    = (const float*)d_in[3];
    const float* attn_W = (const float*)d_in[4];
    const float* attn_b = (const float*)d_in[5];
    const float* comb_W = (const float*)d_in[6];
    const float* comb_b = (const float*)d_in[7];
    const float* Wih0   = (const float*)d_in[8];
    const float* Whh0   = (const float*)d_in[9];
    const float* bih0   = (const float*)d_in[10];
    const float* bhh0   = (const float*)d_in[11];
    const float* Wih1   = (const float*)d_in[12];
    const float* Whh1   = (const float*)d_in[13];
    const float* bih1   = (const float*)d_in[14];
    const float* bhh1   = (const float*)d_in[15];
    const float* out_W  = (const float*)d_in[16];
    const float* out_b  = (const float*)d_in[17];

    float* pred = (float*)d_out;
    float* h1   = pred + 262144;
    float* h2   = h1 + 524288;
    float* c1   = h2 + 524288;
    float* c2   = c1 + 524288;
    const float* h0_l0 = h0;
    const float* h0_l1 = h0 + 524288;
    const float* c0_l0 = c0;
    const float* c0_l1 = c0 + 524288;

    // Aliases inside d_out:
    //   xin aliases pred       (read step 4; pred written step 9)
    //   attn_out aliases c2    (read step 2; c2 written step 7)
    // d_ws: P (lstm partials, 32 MB) / Pg (gemm partials, 8 MB) share base.
    float* xin      = pred;
    float* attn_out = c2;
    float* P        = (float*)d_ws;
    float* Pg       = (float*)d_ws;

    // 1. fused attention -> attn_out
    attn_fused<<<dim3(BB), dim3(512), 0, stream>>>(x, h0_l0, enc, attn_W, attn_b, attn_out);

    // 2-3. comb: xin = relu([x0|attn] @ comb_W^T + comb_b)
    gemm_part<OO, OO + HH><<<dim3(32, 8), dim3(512), 0, stream>>>(x, attn_out, comb_W, Pg);
    gemm_epi<true><<<dim3(256), dim3(256), 0, stream>>>(Pg, comb_b, xin);

    // 4-5. LSTM layer 0 -> h1, c1
    lstm_gates<OO><<<dim3(64, 4), dim3(512), 0, stream>>>(xin, Wih0, h0_l0, Whh0, P);
    lstm_cell<<<dim3(256), dim3(512), 0, stream>>>(P, bih0, bhh0, c0_l0, h1, c1);

    // 6-7. LSTM layer 1 -> h2, c2
    lstm_gates<HH><<<dim3(64, 4), dim3(512), 0, stream>>>(h1, Wih1, h0_l1, Whh1, P);
    lstm_cell<<<dim3(256), dim3(512), 0, stream>>>(P, bih1, bhh1, c0_l1, h2, c2);

    // 8-9. prediction = h2 @ out_W^T + out_b
    gemm_part<HH, HH><<<dim3(32, 8), dim3(512), 0, stream>>>(h2, h2, out_W, Pg);
    gemm_epi<false><<<dim3(256), dim3(256), 0, stream>>>(Pg, out_b, pred);
}